// Round 6
// baseline (970.740 us; speedup 1.0000x reference)
//
#include <hip/hip_runtime.h>
#include <hip/hip_bf16.h>
#include <math.h>

// Problem constants: B=64, C=20, K=5, Q=15, D=2048
#define BATCH 64
#define NCLS  20
#define NS    100   // C*K
#define NQ    300   // C*Q
#define DIM   2048
#define MS    (BATCH * NS)   // 6400
#define MQ    (BATCH * NQ)   // 19200
#define KSPL  4              // k-split factor for sim GEMM
#define PROW  320            // padded rows per batch in partial buffer
#define PCOL  112            // padded cols per batch in partial buffer

typedef __attribute__((ext_vector_type(8))) short frag_ab;   // 8 bf16 (4 VGPRs)
typedef __attribute__((ext_vector_type(4))) float frag_cd;   // 4 fp32 acc

union FAB { frag_ab f; unsigned u[4]; };

// round-to-nearest-even bf16 hi part, returned as fp32 bit pattern
__device__ __forceinline__ unsigned rne_hi(float x) {
  unsigned u = __float_as_uint(x);
  return (u + 0x7FFFu + ((u >> 16) & 1u)) & 0xFFFF0000u;
}

// 2-level RNE split of pair (x,y): x ~= x1 + x2, |residual| <= 2^-18|x|.
__device__ __forceinline__ void split2rn(float x, float y, unsigned& p1,
                                         unsigned& p2) {
  union { __hip_bfloat162 h; unsigned u; } c1, c2;
  c1.h = __float22bfloat162_rn(make_float2(x, y));
  p1 = c1.u;
  float rx = x - __uint_as_float(c1.u << 16);
  float ry = y - __uint_as_float(c1.u & 0xFFFF0000u);
  c2.h = __float22bfloat162_rn(make_float2(rx, ry));
  p2 = c2.u;
}

__device__ __forceinline__ float bf16_f(unsigned short s) {
  return __uint_as_float(((unsigned)s) << 16);
}

#define GLL16(g, l)                                                            \
  __builtin_amdgcn_global_load_lds(                                            \
      (const __attribute__((address_space(1))) void*)(g),                      \
      (__attribute__((address_space(3))) void*)(l), 16, 0, 0)

// ---------------------------------------------------------------------------
// Elementwise 2-level RNE split fp32 -> bf16 hi/mid (layout preserved).
// Used for support (row-major [row][k] = A operand of Z-gemm).
// ---------------------------------------------------------------------------
__global__ __launch_bounds__(256) void esplit2(const float* __restrict__ X,
                                               unsigned short* __restrict__ X1,
                                               unsigned short* __restrict__ X2,
                                               int n4) {
  int i = blockIdx.x * 256 + threadIdx.x;  // handles 4 floats
  if (i >= n4) return;
  float4 v = ((const float4*)X)[i];
  float x[4] = {v.x, v.y, v.z, v.w};
  ushort4 o1, o2;
  unsigned short* d1 = (unsigned short*)&o1;
  unsigned short* d2 = (unsigned short*)&o2;
#pragma unroll
  for (int q = 0; q < 4; ++q) {
    unsigned u1 = rne_hi(x[q]);
    float r1 = x[q] - __uint_as_float(u1);
    unsigned u2 = rne_hi(r1);
    d1[q] = (unsigned short)(u1 >> 16);
    d2[q] = (unsigned short)(u2 >> 16);
  }
  ((ushort4*)X1)[i] = o1;
  ((ushort4*)X2)[i] = o2;
}

// ---------------------------------------------------------------------------
// Fused W preprocessing: per-row 2-level split (W1/W2) + wb[row] = W_row . b;
// block 0 additionally computes bb = ||b||^2. One block per W row.
// ---------------------------------------------------------------------------
__global__ __launch_bounds__(256) void esplit2w(const float* __restrict__ W,
                                                const float* __restrict__ b,
                                                unsigned short* __restrict__ W1,
                                                unsigned short* __restrict__ W2,
                                                float* __restrict__ wb,
                                                float* __restrict__ bb) {
  const int row = blockIdx.x;
  const int d0 = threadIdx.x * 8;
  const float* wr = W + (size_t)row * DIM + d0;
  float4 x0 = *(const float4*)wr, x1 = *(const float4*)(wr + 4);
  float4 b0 = *(const float4*)(b + d0), b1 = *(const float4*)(b + d0 + 4);
  // split 8 elems
  float xs[8] = {x0.x, x0.y, x0.z, x0.w, x1.x, x1.y, x1.z, x1.w};
  ushort4 o1a, o2a, o1b, o2b;
  unsigned short* p1a = (unsigned short*)&o1a;
  unsigned short* p2a = (unsigned short*)&o2a;
  unsigned short* p1b = (unsigned short*)&o1b;
  unsigned short* p2b = (unsigned short*)&o2b;
#pragma unroll
  for (int q = 0; q < 4; ++q) {
    unsigned u1 = rne_hi(xs[q]);
    float r1 = xs[q] - __uint_as_float(u1);
    unsigned u2 = rne_hi(r1);
    p1a[q] = (unsigned short)(u1 >> 16);
    p2a[q] = (unsigned short)(u2 >> 16);
    unsigned v1 = rne_hi(xs[q + 4]);
    float r2 = xs[q + 4] - __uint_as_float(v1);
    unsigned v2 = rne_hi(r2);
    p1b[q] = (unsigned short)(v1 >> 16);
    p2b[q] = (unsigned short)(v2 >> 16);
  }
  *(ushort4*)&W1[(size_t)row * DIM + d0] = o1a;
  *(ushort4*)&W1[(size_t)row * DIM + d0 + 4] = o1b;
  *(ushort4*)&W2[(size_t)row * DIM + d0] = o2a;
  *(ushort4*)&W2[(size_t)row * DIM + d0 + 4] = o2b;
  // wb dot
  float s = x0.x * b0.x + x0.y * b0.y + x0.z * b0.z + x0.w * b0.w +
            x1.x * b1.x + x1.y * b1.y + x1.z * b1.z + x1.w * b1.w;
#pragma unroll
  for (int off = 32; off; off >>= 1) s += __shfl_down(s, off, 64);
  __shared__ float red[4];
  if ((threadIdx.x & 63) == 0) red[threadIdx.x >> 6] = s;
  __syncthreads();
  if (threadIdx.x == 0) wb[row] = red[0] + red[1] + red[2] + red[3];
  if (row == 0) {
    float s2 = b0.x * b0.x + b0.y * b0.y + b0.z * b0.z + b0.w * b0.w +
               b1.x * b1.x + b1.y * b1.y + b1.z * b1.z + b1.w * b1.w;
#pragma unroll
    for (int off = 32; off; off >>= 1) s2 += __shfl_down(s2, off, 64);
    __syncthreads();
    if ((threadIdx.x & 63) == 0) red[threadIdx.x >> 6] = s2;
    __syncthreads();
    if (threadIdx.x == 0) bb[0] = red[0] + red[1] + red[2] + red[3];
  }
}

// ---------------------------------------------------------------------------
// All-bf16 pre-split MFMA GEMM, 3 terms. A1/A2 [m][k], B1/B2 [n][k] 2-level
// RNE splits; terms a1b1+a1b2+a2b1. Block tile 128 x (128*NH), BK=32,
// 4 waves 2x2. Bijective XCD swizzle (requires gridDim.x*gridDim.y % 8 == 0):
// each XCD owns a contiguous tile range -> A-panel L2 reuse.
// Epilogue: optional fp32 Y + fused 2-level RNE split S1o/S2o.
// R5 lesson: stall-bound at 1.5 blocks/CU; NH=1 + 800 blocks -> ~3/CU
// co-residency hides the per-k-tile barrier drain (m114 mechanism).
// ---------------------------------------------------------------------------
template <int NH, int MINW>
__global__ __launch_bounds__(256, MINW) void gemm_bb3(
    const unsigned short* __restrict__ A1, const unsigned short* __restrict__ A2,
    const unsigned short* __restrict__ B1, const unsigned short* __restrict__ B2,
    float* __restrict__ Y, unsigned short* __restrict__ S1o,
    unsigned short* __restrict__ S2o) {
  __shared__ __align__(16) unsigned short A1s[4][128][8];        // 8KB
  __shared__ __align__(16) unsigned short A2s[4][128][8];        // 8KB
  __shared__ __align__(16) unsigned short B1s[4][128 * NH][8];   // 8/16KB
  __shared__ __align__(16) unsigned short B2s[4][128 * NH][8];   // 8/16KB

  const int tid = threadIdx.x;
  const int w = tid >> 6, lane = tid & 63;
  const int ml = lane & 15, kq = lane >> 4;
  const int wm = (w >> 1) * 64, wn = (w & 1) * 64;

  // bijective XCD swizzle
  const int nwgx = gridDim.x;
  const int nwg = nwgx * gridDim.y;
  const int wg = blockIdx.x + nwgx * blockIdx.y;
  const int qq = nwg >> 3;
  const int swz = (wg & 7) * qq + (wg >> 3);
  const int col0 = (swz % nwgx) * (128 * NH);
  const int row0 = (swz / nwgx) * 128;

  frag_cd acc[NH][4][4];
#pragma unroll
  for (int h = 0; h < NH; ++h)
#pragma unroll
    for (int i = 0; i < 4; ++i)
#pragma unroll
      for (int j = 0; j < 4; ++j)
#pragma unroll
        for (int r = 0; r < 4; ++r) acc[h][i][j][r] = 0.f;

  for (int k0 = 0; k0 < DIM; k0 += 32) {
    // ---- stage A (2 splits x 2 row-halves): wave w covers k=k0+w*8..+7 ----
#pragma unroll
    for (int mh = 0; mh < 2; ++mh) {
      const size_t off = (size_t)(row0 + mh * 64 + lane) * DIM + k0 + w * 8;
      GLL16(A1 + off, &A1s[w][mh * 64][0]);
      GLL16(A2 + off, &A2s[w][mh * 64][0]);
    }
    // ---- stage B (2 splits x 128*NH cols) ----
#pragma unroll
    for (int t = 0; t < 2 * NH; ++t) {
      const size_t off = (size_t)(col0 + t * 64 + lane) * DIM + k0 + w * 8;
      GLL16(B1 + off, &B1s[w][t * 64][0]);
      GLL16(B2 + off, &B2s[w][t * 64][0]);
    }
    __syncthreads();

    // ---- A frags: straight 16B LDS reads, no split math ----
    FAB a1[4], a2[4];
#pragma unroll
    for (int i = 0; i < 4; ++i) {
      int m = wm + i * 16 + ml;
      *(uint4*)&a1[i].u[0] = *(const uint4*)&A1s[kq][m][0];
      *(uint4*)&a2[i].u[0] = *(const uint4*)&A2s[kq][m][0];
    }
    // ---- NH column halves x 16 frag-pairs x 3 MFMA terms ----
#pragma unroll
    for (int nh = 0; nh < NH; ++nh) {
#pragma unroll
      for (int j = 0; j < 4; ++j) {
        int n = nh * 128 + wn + j * 16 + ml;
        FAB b1, b2;
        *(uint4*)&b1.u[0] = *(const uint4*)&B1s[kq][n][0];
        *(uint4*)&b2.u[0] = *(const uint4*)&B2s[kq][n][0];
#pragma unroll
        for (int i = 0; i < 4; ++i) {
          acc[nh][i][j] = __builtin_amdgcn_mfma_f32_16x16x32_bf16(
              a1[i].f, b1.f, acc[nh][i][j], 0, 0, 0);
          acc[nh][i][j] = __builtin_amdgcn_mfma_f32_16x16x32_bf16(
              a1[i].f, b2.f, acc[nh][i][j], 0, 0, 0);
          acc[nh][i][j] = __builtin_amdgcn_mfma_f32_16x16x32_bf16(
              a2[i].f, b1.f, acc[nh][i][j], 0, 0, 0);
        }
      }
    }
    __syncthreads();
  }

  // epilogue: C/D layout col=lane&15, row=(lane>>4)*4+reg; fused split.
#pragma unroll
  for (int nh = 0; nh < NH; ++nh)
#pragma unroll
    for (int j = 0; j < 4; ++j) {
      int col = col0 + nh * 128 + wn + j * 16 + ml;
#pragma unroll
      for (int i = 0; i < 4; ++i) {
        int rowb = row0 + wm + i * 16 + kq * 4;
#pragma unroll
        for (int r = 0; r < 4; ++r) {
          float val = acc[nh][i][j][r];
          size_t idx = (size_t)(rowb + r) * DIM + col;
          if (Y) Y[idx] = val;
          unsigned u1 = rne_hi(val);
          float rr = val - __uint_as_float(u1);
          unsigned u2 = rne_hi(rr);
          S1o[idx] = (unsigned short)(u1 >> 16);
          S2o[idx] = (unsigned short)(u2 >> 16);
        }
      }
    }
}

// ---------------------------------------------------------------------------
// Batched sim GEMM partials via MFMA split-3, LDS-free, k-split x4.
// Grid (5, 64, 4) = (m-tile, batch, k-chunk); 1280 blocks, 4 waves each.
// All state in NAMED registers (no arrays -> no scratch demotion).
// part[ks][b][320][112]: padded, maskless epilogue (pads never read).
// Also fuses the u = Xq . wb partial dot; upart[ks][b][320].
// ---------------------------------------------------------------------------
#define MFMA3(ACC, A1, A2, BV1, BV2)                                           \
  ACC = __builtin_amdgcn_mfma_f32_16x16x32_bf16(A1.f, BV1.f, ACC, 0, 0, 0);    \
  ACC = __builtin_amdgcn_mfma_f32_16x16x32_bf16(A1.f, BV2.f, ACC, 0, 0, 0);    \
  ACC = __builtin_amdgcn_mfma_f32_16x16x32_bf16(A2.f, BV1.f, ACC, 0, 0, 0)

#define SIMJ(J)                                                                \
  {                                                                            \
    FAB bf1, bf2;                                                              \
    *(uint4*)&bf1.u[0] = *(const uint4*)(z1b + o##J + k0);                     \
    *(uint4*)&bf2.u[0] = *(const uint4*)(z2b + o##J + k0);                     \
    MFMA3(acc##J, a1, a2, bf1, bf2);                                           \
  }

#define STJ(J)                                                                 \
  {                                                                            \
    const int n = J * 16 + ml;                                                 \
    part[pbase + 0 * PCOL + n] = acc##J[0];                                    \
    part[pbase + 1 * PCOL + n] = acc##J[1];                                    \
    part[pbase + 2 * PCOL + n] = acc##J[2];                                    \
    part[pbase + 3 * PCOL + n] = acc##J[3];                                    \
  }

__global__ __launch_bounds__(256) void sim2_part(
    const float* __restrict__ Xq, const unsigned short* __restrict__ Z1,
    const unsigned short* __restrict__ Z2, const float* __restrict__ wb,
    float* __restrict__ part, float* __restrict__ upart) {
  // bijective XCD swizzle over 1280 blocks: each XCD owns 8 whole batches.
  const int wg = blockIdx.x + 5 * blockIdx.y + 320 * blockIdx.z;
  const int swz = (wg & 7) * 160 + (wg >> 3);
  const int b = swz / 20;
  const int r20 = swz % 20;
  const int ks = r20 / 5;   // k-chunk (0..3)
  const int mt = r20 % 5;   // m-tile within batch (0..4)

  const int w = threadIdx.x >> 6, lane = threadIdx.x & 63;
  const int ml = lane & 15, kq = lane >> 4;

  // A row for this lane (clamped; clamped rows land in pad, never read)
  int r = mt * 64 + w * 16 + ml;
  const int rc = r < NQ ? r : NQ - 1;
  const float* aptr = Xq + ((size_t)b * NQ + rc) * DIM + kq * 8;

  // B bases + 7 static element offsets (clamped cols land in pad)
  const unsigned short* z1b = Z1 + (size_t)b * NS * DIM + kq * 8;
  const unsigned short* z2b = Z2 + (size_t)b * NS * DIM + kq * 8;
  const int o0 = (0 * 16 + ml) * DIM;
  const int o1 = (1 * 16 + ml) * DIM;
  const int o2 = (2 * 16 + ml) * DIM;
  const int o3 = (3 * 16 + ml) * DIM;
  const int o4 = (4 * 16 + ml) * DIM;
  const int o5 = (5 * 16 + ml) * DIM;
  const int n6 = 6 * 16 + ml;
  const int o6 = (n6 < NS ? n6 : NS - 1) * DIM;

  frag_cd acc0 = {0.f, 0.f, 0.f, 0.f}, acc1 = {0.f, 0.f, 0.f, 0.f};
  frag_cd acc2 = {0.f, 0.f, 0.f, 0.f}, acc3 = {0.f, 0.f, 0.f, 0.f};
  frag_cd acc4 = {0.f, 0.f, 0.f, 0.f}, acc5 = {0.f, 0.f, 0.f, 0.f};
  frag_cd acc6 = {0.f, 0.f, 0.f, 0.f};
  float up = 0.f;  // partial u = Xq_row . wb over this k-chunk (this lane's k)

  const int kbeg = ks * (DIM / KSPL), kend = kbeg + DIM / KSPL;
#pragma unroll 2
  for (int k0 = kbeg; k0 < kend; k0 += 32) {
    float4 f0 = *(const float4*)(aptr + k0);      // k = kq*8 + 0..3
    float4 f1 = *(const float4*)(aptr + k0 + 4);  // k = kq*8 + 4..7
    float4 wa = *(const float4*)(wb + k0 + kq * 8);
    float4 wc = *(const float4*)(wb + k0 + kq * 8 + 4);
    up += f0.x * wa.x + f0.y * wa.y + f0.z * wa.z + f0.w * wa.w +
          f1.x * wc.x + f1.y * wc.y + f1.z * wc.z + f1.w * wc.w;
    FAB a1, a2;
    split2rn(f0.x, f0.y, a1.u[0], a2.u[0]);
    split2rn(f0.z, f0.w, a1.u[1], a2.u[1]);
    split2rn(f1.x, f1.y, a1.u[2], a2.u[2]);
    split2rn(f1.z, f1.w, a1.u[3], a2.u[3]);
    SIMJ(0); SIMJ(1); SIMJ(2); SIMJ(3); SIMJ(4); SIMJ(5); SIMJ(6);
  }

  // cross-kq reduce u partial (4 lanes per row: lane = kq*16 + ml)
  up += __shfl_xor(up, 16, 64);
  up += __shfl_xor(up, 32, 64);
  if (lane < 16)
    upart[((size_t)ks * BATCH + b) * PROW + mt * 64 + w * 16 + ml] = up;

  // epilogue: C/D layout col=lane&15, row=(lane>>4)*4+reg; maskless.
  const size_t pbase =
      (((size_t)ks * BATCH + b) * PROW + (mt * 64 + w * 16 + kq * 4)) * PCOL;
  STJ(0); STJ(1); STJ(2); STJ(3); STJ(4); STJ(5); STJ(6);
}

// ---------------------------------------------------------------------------
// ||s_n||^2 from Z splits: z ~= Z1+Z2 (err 2^-18 rel, negligible in a norm).
// nn = (Z1+Z2).Xs + 2*Xs.wb + bb ; outputs inv_norm and v = Xs.wb
// ---------------------------------------------------------------------------
__global__ __launch_bounds__(256) void norm_v2(
    const unsigned short* __restrict__ Z1, const unsigned short* __restrict__ Z2,
    const float* __restrict__ Xs, const float* __restrict__ wb,
    const float* __restrict__ bb, float* __restrict__ inv_norm,
    float* __restrict__ vv) {
  const int row = blockIdx.x;
  const int d0 = threadIdx.x * 8;
  union { uint4 u; unsigned short s[8]; } z1v, z2v;
  z1v.u = *(const uint4*)(Z1 + (size_t)row * DIM + d0);
  z2v.u = *(const uint4*)(Z2 + (size_t)row * DIM + d0);
  const float* xp = Xs + (size_t)row * DIM + d0;
  float4 x0 = *(const float4*)xp, x1 = *(const float4*)(xp + 4);
  float4 w0 = *(const float4*)(wb + d0), w1 = *(const float4*)(wb + d0 + 4);
  float xs[8] = {x0.x, x0.y, x0.z, x0.w, x1.x, x1.y, x1.z, x1.w};
  float s1 = 0.f;
#pragma unroll
  for (int i = 0; i < 8; ++i)
    s1 += (bf16_f(z1v.s[i]) + bf16_f(z2v.s[i])) * xs[i];
  float s2 = x0.x * w0.x + x0.y * w0.y + x0.z * w0.z + x0.w * w0.w +
             x1.x * w1.x + x1.y * w1.y + x1.z * w1.z + x1.w * w1.w;
#pragma unroll
  for (int off = 32; off; off >>= 1) {
    s1 += __shfl_down(s1, off, 64);
    s2 += __shfl_down(s2, off, 64);
  }
  __shared__ float r1[4], r2[4];
  if ((threadIdx.x & 63) == 0) {
    r1[threadIdx.x >> 6] = s1;
    r2[threadIdx.x >> 6] = s2;
  }
  __syncthreads();
  if (threadIdx.x == 0) {
    float t1 = r1[0] + r1[1] + r1[2] + r1[3];
    float t2 = r2[0] + r2[1] + r2[2] + r2[3];
    float nn = t1 + 2.f * t2 + bb[0];
    inv_norm[row] = rsqrtf(fmaxf(nn, 1e-10f));
    vv[row] = t2;
  }
}

// ---------------------------------------------------------------------------
// 4-way partial sum + affine + softmax(100) -> one-hot contract (20)
// -> probs + argmax(pred as float)
// ---------------------------------------------------------------------------
__global__ __launch_bounds__(256) void softmax_part(
    const float* __restrict__ part, const float* __restrict__ upart,
    const float* __restrict__ vv, const float* __restrict__ bb,
    const float* __restrict__ inv_norm, const float* __restrict__ onehot,
    float* __restrict__ out) {
  const int wave = threadIdx.x >> 6;
  const int lane = threadIdx.x & 63;
  const int r = blockIdx.x * 4 + wave;   // global query row
  const int b = r / NQ;
  const int m = r - b * NQ;
  const size_t kstr = (size_t)BATCH * PROW * PCOL;
  const size_t ustr = (size_t)BATCH * PROW;
  const float* p0 = part + ((size_t)b * PROW + m) * PCOL;
  const float* up0 = upart + (size_t)b * PROW + m;
  const float bbv = bb[0];
  const float ur = up0[0] + up0[ustr] + up0[2 * ustr] + up0[3 * ustr];

  // n = lane (always < 100)
  float raw1 = p0[lane] + p0[kstr + lane] + p0[2 * kstr + lane] +
               p0[3 * kstr + lane];
  float v1 = (raw1 + ur + vv[b * NS + lane] + bbv) * inv_norm[b * NS + lane];
  // n = lane + 64 (valid when lane < 36)
  float v2 = -INFINITY;
  if (lane < NS - 64) {
    const int n = lane + 64;
    float raw2 = p0[n] + p0[kstr + n] + p0[2 * kstr + n] + p0[3 * kstr + n];
    v2 = (raw2 + ur + vv[b * NS + n] + bbv) * inv_norm[b * NS + n];
  }
  float mx = fmaxf(v1, v2);
#pragma unroll
  for (int off = 32; off; off >>= 1) mx = fmaxf(mx, __shfl_xor(mx, off, 64));
  float e1 = expf(v1 - mx);
  float e2 = (lane < NS - 64) ? expf(v2 - mx) : 0.f;
  float ssum = e1 + e2;
#pragma unroll
  for (int off = 32; off; off >>= 1) ssum += __shfl_xor(ssum, off, 64);
  float inv = 1.0f / ssum;
  __shared__ float att[4][NS];
  __shared__ float pr[4][NCLS];
  att[wave][lane] = e1 * inv;
  if (lane < NS - 64) att[wave][lane + 64] = e2 * inv;
  __syncthreads();
  if (lane < NCLS) {
    const float* oh = onehot + ((size_t)b * NS) * NCLS + lane;
    float p = 0.f;
#pragma unroll 4
    for (int j = 0; j < NS; ++j) p += att[wave][j] * oh[(size_t)j * NCLS];
    out[(size_t)r * NCLS + lane] = p;
    pr[wave][lane] = p;
  }
  __syncthreads();
  if (lane == 0) {
    int best = 0;
    float bv = pr[wave][0];
    for (int c = 1; c < NCLS; ++c) {
      float v = pr[wave][c];
      if (v > bv) { bv = v; best = c; }
    }
    out[(size_t)MQ * NCLS + r] = (float)best;
  }
}

// ---------------------------------------------------------------------------
// Fallback softmax on materialized sim (small-ws path).
// ---------------------------------------------------------------------------
__global__ __launch_bounds__(256) void softmax_fb(
    const float* __restrict__ sim, const float* __restrict__ onehot,
    float* __restrict__ out) {
  const int wave = threadIdx.x >> 6;
  const int lane = threadIdx.x & 63;
  const int r = blockIdx.x * 4 + wave;
  const int b = r / NQ;
  const float* srow = sim + (size_t)r * NS;
  float v1 = srow[lane];
  float v2 = (lane < NS - 64) ? srow[lane + 64] : -INFINITY;
  float m = fmaxf(v1, v2);
#pragma unroll
  for (int off = 32; off; off >>= 1) m = fmaxf(m, __shfl_xor(m, off, 64));
  float e1 = expf(v1 - m);
  float e2 = (lane < NS - 64) ? expf(v2 - m) : 0.f;
  float ssum = e1 + e2;
#pragma unroll
  for (int off = 32; off; off >>= 1) ssum += __shfl_xor(ssum, off, 64);
  float inv = 1.0f / ssum;
  __shared__ float att[4][NS];
  __shared__ float pr[4][NCLS];
  att[wave][lane] = e1 * inv;
  if (lane < NS - 64) att[wave][lane + 64] = e2 * inv;
  __syncthreads();
  if (lane < NCLS) {
    const float* oh = onehot + ((size_t)b * NS) * NCLS + lane;
    float p = 0.f;
#pragma unroll 4
    for (int j = 0; j < NS; ++j) p += att[wave][j] * oh[(size_t)j * NCLS];
    out[(size_t)r * NCLS + lane] = p;
    pr[wave][lane] = p;
  }
  __syncthreads();
  if (lane == 0) {
    int best = 0;
    float bv = pr[wave][0];
    for (int c = 1; c < NCLS; ++c) {
      float v = pr[wave][c];
      if (v > bv) { bv = v; best = c; }
    }
    out[(size_t)MQ * NCLS + r] = (float)best;
  }
}

// ---------------------------------------------------------------------------
// Fallback fp32 GEMM path kernels (proven R1 path)
// ---------------------------------------------------------------------------
__global__ __launch_bounds__(256) void gemm_xw(const float* __restrict__ X,
                                               const float* __restrict__ W,
                                               const float* __restrict__ bias,
                                               float* __restrict__ Y) {
  __shared__ float As[16][64];
  __shared__ float Bs[16][64];
  const int t = threadIdx.x;
  const int row0 = blockIdx.x * 64;
  const int col0 = blockIdx.y * 64;
  const int am = t >> 2, ak = (t & 3) * 4;
  const int bk = t >> 4, bn = (t & 15) * 4;
  const int tm = (t >> 4) * 4, tn = (t & 15) * 4;
  float acc[4][4] = {};
  for (int k0 = 0; k0 < DIM; k0 += 16) {
    float4 av = *(const float4*)(X + (size_t)(row0 + am) * DIM + k0 + ak);
    As[ak + 0][am] = av.x;
    As[ak + 1][am] = av.y;
    As[ak + 2][am] = av.z;
    As[ak + 3][am] = av.w;
    *(float4*)&Bs[bk][bn] =
        *(const float4*)(W + (size_t)(k0 + bk) * DIM + col0 + bn);
    __syncthreads();
#pragma unroll
    for (int k = 0; k < 16; ++k) {
      float4 a4 = *(const float4*)&As[k][tm];
      float4 b4 = *(const float4*)&Bs[k][tn];
      float av_[4] = {a4.x, a4.y, a4.z, a4.w};
      float bv_[4] = {b4.x, b4.y, b4.z, b4.w};
#pragma unroll
      for (int i = 0; i < 4; ++i)
#pragma unroll
        for (int j = 0; j < 4; ++j) acc[i][j] += av_[i] * bv_[j];
    }
    __syncthreads();
  }
  float4 bbv = *(const float4*)(bias + col0 + tn);
  float bv_[4] = {bbv.x, bbv.y, bbv.z, bbv.w};
#pragma unroll
  for (int i = 0; i < 4; ++i) {
    float4 o;
    o.x = acc[i][0] + bv_[0];
    o.y = acc[i][1] + bv_[1];
    o.z = acc[i][2] + bv_[2];
    o.w = acc[i][3] + bv_[3];
    *(float4*)(Y + (size_t)(row0 + tm + i) * DIM + col0 + tn) = o;
  }
}

__global__ __launch_bounds__(256) void norm_kernel(const float* __restrict__ s,
                                                   float* __restrict__ inv_norm) {
  const int row = blockIdx.x;
  const float* p = s + (size_t)row * DIM;
  const int d0 = threadIdx.x * 8;
  float4 a = *(const float4*)(p + d0);
  float4 b = *(const float4*)(p + d0 + 4);
  float sum = a.x * a.x + a.y * a.y + a.z * a.z + a.w * a.w +
              b.x * b.x + b.y * b.y + b.z * b.z + b.w * b.w;
#pragma unroll
  for (int off = 32; off; off >>= 1) sum += __shfl_down(sum, off, 64);
  __shared__ float red[4];
  if ((threadIdx.x & 63) == 0) red[threadIdx.x >> 6] = sum;
  __syncthreads();
  if (threadIdx.x == 0) {
    float tot = red[0] + red[1] + red[2] + red[3];
    inv_norm[row] = rsqrtf(fmaxf(tot, 1e-10f));
  }
}

__global__ __launch_bounds__(256) void sim_kernel(const float* __restrict__ q,
                                                  const float* __restrict__ s,
                                                  const float* __restrict__ inv_norm,
                                                  float* __restrict__ sim) {
  __shared__ float As[16][64];
  __shared__ float Bs[16][64];
  const int t = threadIdx.x;
  const int b = blockIdx.z;
  const int row0 = blockIdx.y * 64;
  const int col0 = blockIdx.x * 64;
  const float* qb = q + (size_t)b * NQ * DIM;
  const float* sb = s + (size_t)b * NS * DIM;
  const int am = t >> 2, ak = (t & 3) * 4;
  const int tm = (t >> 4) * 4, tn = (t & 15) * 4;
  float acc[4][4] = {};
  for (int k0 = 0; k0 < DIM; k0 += 16) {
    float4 av = make_float4(0.f, 0.f, 0.f, 0.f);
    if (row0 + am < NQ)
      av = *(const float4*)(qb + (size_t)(row0 + am) * DIM + k0 + ak);
    As[ak + 0][am] = av.x;
    As[ak + 1][am] = av.y;
    As[ak + 2][am] = av.z;
    As[ak + 3][am] = av.w;
    float4 bv = make_float4(0.f, 0.f, 0.f, 0.f);
    if (col0 + am < NS)
      bv = *(const float4*)(sb + (size_t)(col0 + am) * DIM + k0 + ak);
    Bs[ak + 0][am] = bv.x;
    Bs[ak + 1][am] = bv.y;
    Bs[ak + 2][am] = bv.z;
    Bs[ak + 3][am] = bv.w;
    __syncthreads();
#pragma unroll
    for (int k = 0; k < 16; ++k) {
      float4 a4 = *(const float4*)&As[k][tm];
      float4 b4 = *(const float4*)&Bs[k][tn];
      float av_[4] = {a4.x, a4.y, a4.z, a4.w};
      float bv_[4] = {b4.x, b4.y, b4.z, b4.w};
#pragma unroll
      for (int i = 0; i < 4; ++i)
#pragma unroll
        for (int j = 0; j < 4; ++j) acc[i][j] += av_[i] * bv_[j];
    }
    __syncthreads();
  }
#pragma unroll
  for (int i = 0; i < 4; ++i) {
    int m = row0 + tm + i;
    if (m >= NQ) continue;
#pragma unroll
    for (int j = 0; j < 4; ++j) {
      int n = col0 + tn + j;
      if (n >= NS) continue;
      sim[((size_t)b * NQ + m) * NS + n] = acc[i][j] * inv_norm[b * NS + n];
    }
  }
}

// ---------------------------------------------------------------------------
extern "C" void kernel_launch(void* const* d_in, const int* in_sizes, int n_in,
                              void* d_out, int out_size, void* d_ws,
                              size_t ws_size, hipStream_t stream) {
  const float* support = (const float*)d_in[0];
  const float* query   = (const float*)d_in[1];
  const float* onehot  = (const float*)d_in[2];
  const float* W       = (const float*)d_in[3];
  const float* bias    = (const float*)d_in[4];

  char* wsb = (char*)d_ws;

  // --- Gram-matrix path workspace layout (Z fp32 eliminated) ---
  // S1   : 6400*2048*2 = 26,214,400 @ 0
  // S2   :             = 26,214,400 @ 26,214,400
  // Wr1  : 2048*2048*2 =  8,388,608 @ 52,428,800
  // Wr2  :             =  8,388,608 @ 60,817,408
  // G1   :             =  8,388,608 @ 69,206,016
  // G2   :             =  8,388,608 @ 77,594,624
  // Z1   : 6400*2048*2 = 26,214,400 @ 85,983,232
  // Z2   :             = 26,214,400 @ 112,197,632
  // part : 4*64*320*112*4 = 36,700,160 @ 138,412,032
  // inv  : 6400*4 = 25,600 @ 175,112,192
  // vv   : 6400*4 = 25,600 @ 175,137,792
  // wb   : 2048*4 =  8,192 @ 175,163,392
  // bb   : 256 pad        @ 175,171,584
  // upart: 4*64*320*4 = 327,680 @ 175,171,840
  const size_t NEED = 175499520;

  if (ws_size >= NEED) {
    unsigned short* S1    = (unsigned short*)(wsb);
    unsigned short* S2    = (unsigned short*)(wsb + (size_t)26214400);
    unsigned short* Wr1   = (unsigned short*)(wsb + (size_t)52428800);
    unsigned short* Wr2   = (unsigned short*)(wsb + (size_t)60817408);
    unsigned short* G1    = (unsigned short*)(wsb + (size_t)69206016);
    unsigned short* G2    = (unsigned short*)(wsb + (size_t)77594624);
    unsigned short* Z1    = (unsigned short*)(wsb + (size_t)85983232);
    unsigned short* Z2    = (unsigned short*)(wsb + (size_t)112197632);
    float* part           = (float*)(wsb + (size_t)138412032);
    float* inv_norm       = (float*)(wsb + (size_t)175112192);
    float* vv             = (float*)(wsb + (size_t)175137792);
    float* wb             = (float*)(wsb + (size_t)175163392);
    float* bb             = (float*)(wsb + (size_t)175171584);
    float* upart          = (float*)(wsb + (size_t)175171840);

    // W split + wb = W@b + bb (fused); support split
    esplit2w<<<DIM, 256, 0, stream>>>(W, bias, Wr1, Wr2, wb, bb);
    esplit2<<<MS * DIM / 1024, 256, 0, stream>>>(support, S1, S2,
                                                 MS * DIM / 4);
    // G = W @ W^T, all-bf16 128x128, 256 blocks; fused G1/G2 split epilogue.
    gemm_bb3<1, 4><<<dim3(DIM / 128, DIM / 128), 256, 0, stream>>>(
        Wr1, Wr2, Wr1, Wr2, nullptr, G1, G2);
    // Z = Xs @ G, all-bf16 128x128, 800 blocks (~3/CU co-residency hides
    // barrier drain); no fp32 Z — splits only.
    gemm_bb3<1, 4><<<dim3(DIM / 128, MS / 128), 256, 0, stream>>>(
        S1, S2, G1, G2, nullptr, Z1, Z2);
    // norm from Z splits + v = Xs@wb
    norm_v2<<<MS, 256, 0, stream>>>(Z1, Z2, support, wb, bb, inv_norm, vv);
    // sim partials (k-split x4, MFMA, LDS-free) + fused u = Xq.wb partials
    sim2_part<<<dim3(5, BATCH, KSPL), 256, 0, stream>>>(query, Z1, Z2, wb,
                                                        part, upart);
    // partial-sum + affine + softmax + onehot contract + argmax
    softmax_part<<<MQ / 4, 256, 0, stream>>>(part, upart, vv, bb, inv_norm,
                                             onehot, (float*)d_out);
  } else {
    // proven R1 fallback (fits in 217.5 MB)
    float* s = (float*)wsb;
    float* q = (float*)(wsb + (size_t)52428800);
    float* inv_norm = q + (size_t)MQ * DIM;
    float* sim      = inv_norm + MS;
    gemm_xw<<<dim3(MS / 64, DIM / 64), 256, 0, stream>>>(support, W, bias, s);
    gemm_xw<<<dim3(MQ / 64, DIM / 64), 256, 0, stream>>>(query, W, bias, q);
    norm_kernel<<<MS, 256, 0, stream>>>(s, inv_norm);
    sim_kernel<<<dim3(2, 5, BATCH), 256, 0, stream>>>(q, s, inv_norm, sim);
    softmax_fb<<<MQ / 4, 256, 0, stream>>>(sim, onehot, (float*)d_out);
  }
}

// Round 7
// 723.187 us; speedup vs baseline: 1.3423x; 1.3423x over previous
//
#include <hip/hip_runtime.h>
#include <hip/hip_bf16.h>
#include <math.h>

// Problem constants: B=64, C=20, K=5, Q=15, D=2048
#define BATCH 64
#define NCLS  20
#define NS    100   // C*K
#define NQ    300   // C*Q
#define DIM   2048
#define MS    (BATCH * NS)   // 6400
#define MQ    (BATCH * NQ)   // 19200
#define KSPL  4              // k-split factor for sim GEMM
#define PROW  320            // padded rows per batch in partial buffer
#define PCOL  112            // padded cols per batch in partial buffer

typedef __attribute__((ext_vector_type(8))) short frag_ab;   // 8 bf16 (4 VGPRs)
typedef __attribute__((ext_vector_type(4))) float frag_cd;   // 4 fp32 acc

union FAB { frag_ab f; unsigned u[4]; };

// round-to-nearest-even bf16 hi part, returned as fp32 bit pattern
__device__ __forceinline__ unsigned rne_hi(float x) {
  unsigned u = __float_as_uint(x);
  return (u + 0x7FFFu + ((u >> 16) & 1u)) & 0xFFFF0000u;
}

// 2-level RNE split of pair (x,y): x ~= x1 + x2, |residual| <= 2^-18|x|.
__device__ __forceinline__ void split2rn(float x, float y, unsigned& p1,
                                         unsigned& p2) {
  union { __hip_bfloat162 h; unsigned u; } c1, c2;
  c1.h = __float22bfloat162_rn(make_float2(x, y));
  p1 = c1.u;
  float rx = x - __uint_as_float(c1.u << 16);
  float ry = y - __uint_as_float(c1.u & 0xFFFF0000u);
  c2.h = __float22bfloat162_rn(make_float2(rx, ry));
  p2 = c2.u;
}

#define GLL16(g, l)                                                            \
  __builtin_amdgcn_global_load_lds(                                            \
      (const __attribute__((address_space(1))) void*)(g),                      \
      (__attribute__((address_space(3))) void*)(l), 16, 0, 0)

// ---------------------------------------------------------------------------
// Elementwise 2-level RNE split fp32 -> bf16 hi/mid (layout preserved).
// Used for support (row-major [row][k] = A operand of Z-gemm).
// ---------------------------------------------------------------------------
__global__ __launch_bounds__(256) void esplit2(const float* __restrict__ X,
                                               unsigned short* __restrict__ X1,
                                               unsigned short* __restrict__ X2,
                                               int n4) {
  int i = blockIdx.x * 256 + threadIdx.x;  // handles 4 floats
  if (i >= n4) return;
  float4 v = ((const float4*)X)[i];
  float x[4] = {v.x, v.y, v.z, v.w};
  ushort4 o1, o2;
  unsigned short* d1 = (unsigned short*)&o1;
  unsigned short* d2 = (unsigned short*)&o2;
#pragma unroll
  for (int q = 0; q < 4; ++q) {
    unsigned u1 = rne_hi(x[q]);
    float r1 = x[q] - __uint_as_float(u1);
    unsigned u2 = rne_hi(r1);
    d1[q] = (unsigned short)(u1 >> 16);
    d2[q] = (unsigned short)(u2 >> 16);
  }
  ((ushort4*)X1)[i] = o1;
  ((ushort4*)X2)[i] = o2;
}

// ---------------------------------------------------------------------------
// Fused W preprocessing: per-row 2-level split (W1/W2) + wb[row] = W_row . b;
// block 0 additionally computes bb = ||b||^2. One block per W row.
// ---------------------------------------------------------------------------
__global__ __launch_bounds__(256) void esplit2w(const float* __restrict__ W,
                                                const float* __restrict__ b,
                                                unsigned short* __restrict__ W1,
                                                unsigned short* __restrict__ W2,
                                                float* __restrict__ wb,
                                                float* __restrict__ bb) {
  const int row = blockIdx.x;
  const int d0 = threadIdx.x * 8;
  const float* wr = W + (size_t)row * DIM + d0;
  float4 x0 = *(const float4*)wr, x1 = *(const float4*)(wr + 4);
  float4 b0 = *(const float4*)(b + d0), b1 = *(const float4*)(b + d0 + 4);
  float xs[8] = {x0.x, x0.y, x0.z, x0.w, x1.x, x1.y, x1.z, x1.w};
  ushort4 o1a, o2a, o1b, o2b;
  unsigned short* p1a = (unsigned short*)&o1a;
  unsigned short* p2a = (unsigned short*)&o2a;
  unsigned short* p1b = (unsigned short*)&o1b;
  unsigned short* p2b = (unsigned short*)&o2b;
#pragma unroll
  for (int q = 0; q < 4; ++q) {
    unsigned u1 = rne_hi(xs[q]);
    float r1 = xs[q] - __uint_as_float(u1);
    unsigned u2 = rne_hi(r1);
    p1a[q] = (unsigned short)(u1 >> 16);
    p2a[q] = (unsigned short)(u2 >> 16);
    unsigned v1 = rne_hi(xs[q + 4]);
    float r2 = xs[q + 4] - __uint_as_float(v1);
    unsigned v2 = rne_hi(r2);
    p1b[q] = (unsigned short)(v1 >> 16);
    p2b[q] = (unsigned short)(v2 >> 16);
  }
  *(ushort4*)&W1[(size_t)row * DIM + d0] = o1a;
  *(ushort4*)&W1[(size_t)row * DIM + d0 + 4] = o1b;
  *(ushort4*)&W2[(size_t)row * DIM + d0] = o2a;
  *(ushort4*)&W2[(size_t)row * DIM + d0 + 4] = o2b;
  float s = x0.x * b0.x + x0.y * b0.y + x0.z * b0.z + x0.w * b0.w +
            x1.x * b1.x + x1.y * b1.y + x1.z * b1.z + x1.w * b1.w;
#pragma unroll
  for (int off = 32; off; off >>= 1) s += __shfl_down(s, off, 64);
  __shared__ float red[4];
  if ((threadIdx.x & 63) == 0) red[threadIdx.x >> 6] = s;
  __syncthreads();
  if (threadIdx.x == 0) wb[row] = red[0] + red[1] + red[2] + red[3];
  if (row == 0) {
    float s2 = b0.x * b0.x + b0.y * b0.y + b0.z * b0.z + b0.w * b0.w +
               b1.x * b1.x + b1.y * b1.y + b1.z * b1.z + b1.w * b1.w;
#pragma unroll
    for (int off = 32; off; off >>= 1) s2 += __shfl_down(s2, off, 64);
    __syncthreads();
    if ((threadIdx.x & 63) == 0) red[threadIdx.x >> 6] = s2;
    __syncthreads();
    if (threadIdx.x == 0) bb[0] = red[0] + red[1] + red[2] + red[3];
  }
}

// ---------------------------------------------------------------------------
// All-bf16 pre-split MFMA GEMM, 3 terms, K-SPLIT partial output.
// A1/A2 [m][k], B1/B2 [n][k] 2-level RNE splits; terms a1b1+a1b2+a2b1.
// Block tile 128 x 256 (NH=2 fixed: R5/R6 A/B showed 96 MFMA/barrier/wave
// is the dominant efficiency factor; NH=1 halves it and lost 75%).
// Grid (gx, gy, KS): blockIdx.z = k-chunk; each block accumulates K/KS in
// fp32 and writes partials P[ks][row][col]. K-split grows the grid for
// co-residency WITHOUT shrinking per-barrier MFMA density.
// No XCD swizzle (R5-proven plain mapping; R6's swizzle was not isolated-won).
// ---------------------------------------------------------------------------
template <int KS>
__global__ __launch_bounds__(256, 2) void gemm_bb3k(
    const unsigned short* __restrict__ A1, const unsigned short* __restrict__ A2,
    const unsigned short* __restrict__ B1, const unsigned short* __restrict__ B2,
    float* __restrict__ P) {
  __shared__ __align__(16) unsigned short A1s[4][128][8];   // 8KB
  __shared__ __align__(16) unsigned short A2s[4][128][8];   // 8KB
  __shared__ __align__(16) unsigned short B1s[4][256][8];   // 16KB
  __shared__ __align__(16) unsigned short B2s[4][256][8];   // 16KB

  const int tid = threadIdx.x;
  const int w = tid >> 6, lane = tid & 63;
  const int ml = lane & 15, kq = lane >> 4;
  const int wm = (w >> 1) * 64, wn = (w & 1) * 64;
  const int col0 = blockIdx.x * 256, row0 = blockIdx.y * 128;
  const int ks = blockIdx.z;
  const int MROWS = gridDim.y * 128;

  frag_cd acc[2][4][4];
#pragma unroll
  for (int h = 0; h < 2; ++h)
#pragma unroll
    for (int i = 0; i < 4; ++i)
#pragma unroll
      for (int j = 0; j < 4; ++j)
#pragma unroll
        for (int r = 0; r < 4; ++r) acc[h][i][j][r] = 0.f;

  const int kbeg = ks * (DIM / KS), kend = kbeg + DIM / KS;
  for (int k0 = kbeg; k0 < kend; k0 += 32) {
    // ---- stage A (2 splits x 2 row-halves): wave w covers k=k0+w*8..+7 ----
#pragma unroll
    for (int mh = 0; mh < 2; ++mh) {
      const size_t off = (size_t)(row0 + mh * 64 + lane) * DIM + k0 + w * 8;
      GLL16(A1 + off, &A1s[w][mh * 64][0]);
      GLL16(A2 + off, &A2s[w][mh * 64][0]);
    }
    // ---- stage B (2 splits x 4 col-quarters) ----
#pragma unroll
    for (int t = 0; t < 4; ++t) {
      const size_t off = (size_t)(col0 + t * 64 + lane) * DIM + k0 + w * 8;
      GLL16(B1 + off, &B1s[w][t * 64][0]);
      GLL16(B2 + off, &B2s[w][t * 64][0]);
    }
    __syncthreads();

    // ---- A frags: straight 16B LDS reads ----
    FAB a1[4], a2[4];
#pragma unroll
    for (int i = 0; i < 4; ++i) {
      int m = wm + i * 16 + ml;
      *(uint4*)&a1[i].u[0] = *(const uint4*)&A1s[kq][m][0];
      *(uint4*)&a2[i].u[0] = *(const uint4*)&A2s[kq][m][0];
    }
    // ---- 2 column halves x 16 frag-pairs x 3 MFMA terms (96 MFMA/wave) ----
#pragma unroll
    for (int nh = 0; nh < 2; ++nh) {
#pragma unroll
      for (int j = 0; j < 4; ++j) {
        int n = nh * 128 + wn + j * 16 + ml;
        FAB b1, b2;
        *(uint4*)&b1.u[0] = *(const uint4*)&B1s[kq][n][0];
        *(uint4*)&b2.u[0] = *(const uint4*)&B2s[kq][n][0];
#pragma unroll
        for (int i = 0; i < 4; ++i) {
          acc[nh][i][j] = __builtin_amdgcn_mfma_f32_16x16x32_bf16(
              a1[i].f, b1.f, acc[nh][i][j], 0, 0, 0);
          acc[nh][i][j] = __builtin_amdgcn_mfma_f32_16x16x32_bf16(
              a1[i].f, b2.f, acc[nh][i][j], 0, 0, 0);
          acc[nh][i][j] = __builtin_amdgcn_mfma_f32_16x16x32_bf16(
              a2[i].f, b1.f, acc[nh][i][j], 0, 0, 0);
        }
      }
    }
    __syncthreads();
  }

  // epilogue: fp32 partial write; C/D layout col=lane&15, row=(lane>>4)*4+reg
  float* Pk = P + (size_t)ks * MROWS * DIM;
#pragma unroll
  for (int nh = 0; nh < 2; ++nh)
#pragma unroll
    for (int j = 0; j < 4; ++j) {
      int col = col0 + nh * 128 + wn + j * 16 + ml;
#pragma unroll
      for (int i = 0; i < 4; ++i) {
        int rowb = row0 + wm + i * 16 + kq * 4;
#pragma unroll
        for (int r = 0; r < 4; ++r)
          Pk[(size_t)(rowb + r) * DIM + col] = acc[nh][i][j][r];
      }
    }
}

// ---------------------------------------------------------------------------
// redG: sum 4 G partials -> 2-level RNE split -> G1/G2 (no fp32 G kept).
// ---------------------------------------------------------------------------
__global__ __launch_bounds__(256) void redG(const float* __restrict__ Gp,
                                            unsigned short* __restrict__ G1,
                                            unsigned short* __restrict__ G2) {
  const int i = blockIdx.x * 256 + threadIdx.x;  // float4 index
  const size_t n4 = (size_t)DIM * DIM / 4;
  const float4* p0 = (const float4*)Gp;
  float4 a = p0[i];
  float4 b = p0[n4 + i];
  float4 c = p0[2 * n4 + i];
  float4 d = p0[3 * n4 + i];
  float x[4] = {a.x + b.x + c.x + d.x, a.y + b.y + c.y + d.y,
                a.z + b.z + c.z + d.z, a.w + b.w + c.w + d.w};
  ushort4 o1, o2;
  unsigned short* d1 = (unsigned short*)&o1;
  unsigned short* d2 = (unsigned short*)&o2;
#pragma unroll
  for (int q = 0; q < 4; ++q) {
    unsigned u1 = rne_hi(x[q]);
    float r1 = x[q] - __uint_as_float(u1);
    unsigned u2 = rne_hi(r1);
    d1[q] = (unsigned short)(u1 >> 16);
    d2[q] = (unsigned short)(u2 >> 16);
  }
  ((ushort4*)G1)[i] = o1;
  ((ushort4*)G2)[i] = o2;
}

// ---------------------------------------------------------------------------
// redZ: per-row: z = Zp0 + Zp1 (fp32), split -> Z1/Z2, AND fused norm:
// ||s||^2 = z.Xs + 2*Xs.wb + bb -> inv_norm; v = Xs.wb. One block per row.
// ---------------------------------------------------------------------------
__global__ __launch_bounds__(256) void redZ(const float* __restrict__ Zp,
                                            const float* __restrict__ Xs,
                                            const float* __restrict__ wb,
                                            const float* __restrict__ bb,
                                            unsigned short* __restrict__ Z1,
                                            unsigned short* __restrict__ Z2,
                                            float* __restrict__ inv_norm,
                                            float* __restrict__ vv) {
  const int row = blockIdx.x;
  const int d0 = threadIdx.x * 8;
  const size_t kstr = (size_t)MS * DIM;
  const float* zp = Zp + (size_t)row * DIM + d0;
  float4 a0 = *(const float4*)zp, a1 = *(const float4*)(zp + 4);
  float4 b0 = *(const float4*)(zp + kstr), b1 = *(const float4*)(zp + kstr + 4);
  float z[8] = {a0.x + b0.x, a0.y + b0.y, a0.z + b0.z, a0.w + b0.w,
                a1.x + b1.x, a1.y + b1.y, a1.z + b1.z, a1.w + b1.w};
  const float* xp = Xs + (size_t)row * DIM + d0;
  float4 x0 = *(const float4*)xp, x1 = *(const float4*)(xp + 4);
  float4 w0 = *(const float4*)(wb + d0), w1 = *(const float4*)(wb + d0 + 4);
  float xs[8] = {x0.x, x0.y, x0.z, x0.w, x1.x, x1.y, x1.z, x1.w};
  // split + write
  ushort4 o1a, o2a, o1b, o2b;
  unsigned short* p1a = (unsigned short*)&o1a;
  unsigned short* p2a = (unsigned short*)&o2a;
  unsigned short* p1b = (unsigned short*)&o1b;
  unsigned short* p2b = (unsigned short*)&o2b;
#pragma unroll
  for (int q = 0; q < 4; ++q) {
    unsigned u1 = rne_hi(z[q]);
    float r1 = z[q] - __uint_as_float(u1);
    unsigned u2 = rne_hi(r1);
    p1a[q] = (unsigned short)(u1 >> 16);
    p2a[q] = (unsigned short)(u2 >> 16);
    unsigned v1 = rne_hi(z[q + 4]);
    float r2 = z[q + 4] - __uint_as_float(v1);
    unsigned v2 = rne_hi(r2);
    p1b[q] = (unsigned short)(v1 >> 16);
    p2b[q] = (unsigned short)(v2 >> 16);
  }
  *(ushort4*)&Z1[(size_t)row * DIM + d0] = o1a;
  *(ushort4*)&Z1[(size_t)row * DIM + d0 + 4] = o1b;
  *(ushort4*)&Z2[(size_t)row * DIM + d0] = o2a;
  *(ushort4*)&Z2[(size_t)row * DIM + d0 + 4] = o2b;
  // fused norm dots
  float s1 = 0.f;
#pragma unroll
  for (int q = 0; q < 8; ++q) s1 += z[q] * xs[q];
  float s2 = x0.x * w0.x + x0.y * w0.y + x0.z * w0.z + x0.w * w0.w +
             x1.x * w1.x + x1.y * w1.y + x1.z * w1.z + x1.w * w1.w;
#pragma unroll
  for (int off = 32; off; off >>= 1) {
    s1 += __shfl_down(s1, off, 64);
    s2 += __shfl_down(s2, off, 64);
  }
  __shared__ float r1s[4], r2s[4];
  if ((threadIdx.x & 63) == 0) {
    r1s[threadIdx.x >> 6] = s1;
    r2s[threadIdx.x >> 6] = s2;
  }
  __syncthreads();
  if (threadIdx.x == 0) {
    float t1 = r1s[0] + r1s[1] + r1s[2] + r1s[3];
    float t2 = r2s[0] + r2s[1] + r2s[2] + r2s[3];
    float nn = t1 + 2.f * t2 + bb[0];
    inv_norm[row] = rsqrtf(fmaxf(nn, 1e-10f));
    vv[row] = t2;
  }
}

// ---------------------------------------------------------------------------
// Batched sim GEMM partials via MFMA split-3, LDS-free, k-split x4.
// Grid (5, 64, 4); 1280 blocks, 4 waves each. Named registers only.
// part[ks][b][320][112]; fused u = Xq.wb partials in upart[ks][b][320].
// ---------------------------------------------------------------------------
#define MFMA3(ACC, A1, A2, BV1, BV2)                                           \
  ACC = __builtin_amdgcn_mfma_f32_16x16x32_bf16(A1.f, BV1.f, ACC, 0, 0, 0);    \
  ACC = __builtin_amdgcn_mfma_f32_16x16x32_bf16(A1.f, BV2.f, ACC, 0, 0, 0);    \
  ACC = __builtin_amdgcn_mfma_f32_16x16x32_bf16(A2.f, BV1.f, ACC, 0, 0, 0)

#define SIMJ(J)                                                                \
  {                                                                            \
    FAB bf1, bf2;                                                              \
    *(uint4*)&bf1.u[0] = *(const uint4*)(z1b + o##J + k0);                     \
    *(uint4*)&bf2.u[0] = *(const uint4*)(z2b + o##J + k0);                     \
    MFMA3(acc##J, a1, a2, bf1, bf2);                                           \
  }

#define STJ(J)                                                                 \
  {                                                                            \
    const int n = J * 16 + ml;                                                 \
    part[pbase + 0 * PCOL + n] = acc##J[0];                                    \
    part[pbase + 1 * PCOL + n] = acc##J[1];                                    \
    part[pbase + 2 * PCOL + n] = acc##J[2];                                    \
    part[pbase + 3 * PCOL + n] = acc##J[3];                                    \
  }

__global__ __launch_bounds__(256) void sim2_part(
    const float* __restrict__ Xq, const unsigned short* __restrict__ Z1,
    const unsigned short* __restrict__ Z2, const float* __restrict__ wb,
    float* __restrict__ part, float* __restrict__ upart) {
  // bijective XCD swizzle over 1280 blocks: each XCD owns 8 whole batches.
  const int wg = blockIdx.x + 5 * blockIdx.y + 320 * blockIdx.z;
  const int swz = (wg & 7) * 160 + (wg >> 3);
  const int b = swz / 20;
  const int r20 = swz % 20;
  const int ks = r20 / 5;   // k-chunk (0..3)
  const int mt = r20 % 5;   // m-tile within batch (0..4)

  const int w = threadIdx.x >> 6, lane = threadIdx.x & 63;
  const int ml = lane & 15, kq = lane >> 4;

  int r = mt * 64 + w * 16 + ml;
  const int rc = r < NQ ? r : NQ - 1;
  const float* aptr = Xq + ((size_t)b * NQ + rc) * DIM + kq * 8;

  const unsigned short* z1b = Z1 + (size_t)b * NS * DIM + kq * 8;
  const unsigned short* z2b = Z2 + (size_t)b * NS * DIM + kq * 8;
  const int o0 = (0 * 16 + ml) * DIM;
  const int o1 = (1 * 16 + ml) * DIM;
  const int o2 = (2 * 16 + ml) * DIM;
  const int o3 = (3 * 16 + ml) * DIM;
  const int o4 = (4 * 16 + ml) * DIM;
  const int o5 = (5 * 16 + ml) * DIM;
  const int n6 = 6 * 16 + ml;
  const int o6 = (n6 < NS ? n6 : NS - 1) * DIM;

  frag_cd acc0 = {0.f, 0.f, 0.f, 0.f}, acc1 = {0.f, 0.f, 0.f, 0.f};
  frag_cd acc2 = {0.f, 0.f, 0.f, 0.f}, acc3 = {0.f, 0.f, 0.f, 0.f};
  frag_cd acc4 = {0.f, 0.f, 0.f, 0.f}, acc5 = {0.f, 0.f, 0.f, 0.f};
  frag_cd acc6 = {0.f, 0.f, 0.f, 0.f};
  float up = 0.f;

  const int kbeg = ks * (DIM / KSPL), kend = kbeg + DIM / KSPL;
#pragma unroll 2
  for (int k0 = kbeg; k0 < kend; k0 += 32) {
    float4 f0 = *(const float4*)(aptr + k0);
    float4 f1 = *(const float4*)(aptr + k0 + 4);
    float4 wa = *(const float4*)(wb + k0 + kq * 8);
    float4 wc = *(const float4*)(wb + k0 + kq * 8 + 4);
    up += f0.x * wa.x + f0.y * wa.y + f0.z * wa.z + f0.w * wa.w +
          f1.x * wc.x + f1.y * wc.y + f1.z * wc.z + f1.w * wc.w;
    FAB a1, a2;
    split2rn(f0.x, f0.y, a1.u[0], a2.u[0]);
    split2rn(f0.z, f0.w, a1.u[1], a2.u[1]);
    split2rn(f1.x, f1.y, a1.u[2], a2.u[2]);
    split2rn(f1.z, f1.w, a1.u[3], a2.u[3]);
    SIMJ(0); SIMJ(1); SIMJ(2); SIMJ(3); SIMJ(4); SIMJ(5); SIMJ(6);
  }

  up += __shfl_xor(up, 16, 64);
  up += __shfl_xor(up, 32, 64);
  if (lane < 16)
    upart[((size_t)ks * BATCH + b) * PROW + mt * 64 + w * 16 + ml] = up;

  const size_t pbase =
      (((size_t)ks * BATCH + b) * PROW + (mt * 64 + w * 16 + kq * 4)) * PCOL;
  STJ(0); STJ(1); STJ(2); STJ(3); STJ(4); STJ(5); STJ(6);
}

// ---------------------------------------------------------------------------
// 4-way partial sum + affine + softmax(100) -> one-hot contract (20)
// -> probs + argmax(pred as float)
// ---------------------------------------------------------------------------
__global__ __launch_bounds__(256) void softmax_part(
    const float* __restrict__ part, const float* __restrict__ upart,
    const float* __restrict__ vv, const float* __restrict__ bb,
    const float* __restrict__ inv_norm, const float* __restrict__ onehot,
    float* __restrict__ out) {
  const int wave = threadIdx.x >> 6;
  const int lane = threadIdx.x & 63;
  const int r = blockIdx.x * 4 + wave;
  const int b = r / NQ;
  const int m = r - b * NQ;
  const size_t kstr = (size_t)BATCH * PROW * PCOL;
  const size_t ustr = (size_t)BATCH * PROW;
  const float* p0 = part + ((size_t)b * PROW + m) * PCOL;
  const float* up0 = upart + (size_t)b * PROW + m;
  const float bbv = bb[0];
  const float ur = up0[0] + up0[ustr] + up0[2 * ustr] + up0[3 * ustr];

  float raw1 = p0[lane] + p0[kstr + lane] + p0[2 * kstr + lane] +
               p0[3 * kstr + lane];
  float v1 = (raw1 + ur + vv[b * NS + lane] + bbv) * inv_norm[b * NS + lane];
  float v2 = -INFINITY;
  if (lane < NS - 64) {
    const int n = lane + 64;
    float raw2 = p0[n] + p0[kstr + n] + p0[2 * kstr + n] + p0[3 * kstr + n];
    v2 = (raw2 + ur + vv[b * NS + n] + bbv) * inv_norm[b * NS + n];
  }
  float mx = fmaxf(v1, v2);
#pragma unroll
  for (int off = 32; off; off >>= 1) mx = fmaxf(mx, __shfl_xor(mx, off, 64));
  float e1 = expf(v1 - mx);
  float e2 = (lane < NS - 64) ? expf(v2 - mx) : 0.f;
  float ssum = e1 + e2;
#pragma unroll
  for (int off = 32; off; off >>= 1) ssum += __shfl_xor(ssum, off, 64);
  float inv = 1.0f / ssum;
  __shared__ float att[4][NS];
  __shared__ float pr[4][NCLS];
  att[wave][lane] = e1 * inv;
  if (lane < NS - 64) att[wave][lane + 64] = e2 * inv;
  __syncthreads();
  if (lane < NCLS) {
    const float* oh = onehot + ((size_t)b * NS) * NCLS + lane;
    float p = 0.f;
#pragma unroll 4
    for (int j = 0; j < NS; ++j) p += att[wave][j] * oh[(size_t)j * NCLS];
    out[(size_t)r * NCLS + lane] = p;
    pr[wave][lane] = p;
  }
  __syncthreads();
  if (lane == 0) {
    int best = 0;
    float bv = pr[wave][0];
    for (int c = 1; c < NCLS; ++c) {
      float v = pr[wave][c];
      if (v > bv) { bv = v; best = c; }
    }
    out[(size_t)MQ * NCLS + r] = (float)best;
  }
}

// ---------------------------------------------------------------------------
// Fallback softmax on materialized sim (small-ws path).
// ---------------------------------------------------------------------------
__global__ __launch_bounds__(256) void softmax_fb(
    const float* __restrict__ sim, const float* __restrict__ onehot,
    float* __restrict__ out) {
  const int wave = threadIdx.x >> 6;
  const int lane = threadIdx.x & 63;
  const int r = blockIdx.x * 4 + wave;
  const int b = r / NQ;
  const float* srow = sim + (size_t)r * NS;
  float v1 = srow[lane];
  float v2 = (lane < NS - 64) ? srow[lane + 64] : -INFINITY;
  float m = fmaxf(v1, v2);
#pragma unroll
  for (int off = 32; off; off >>= 1) m = fmaxf(m, __shfl_xor(m, off, 64));
  float e1 = expf(v1 - m);
  float e2 = (lane < NS - 64) ? expf(v2 - m) : 0.f;
  float ssum = e1 + e2;
#pragma unroll
  for (int off = 32; off; off >>= 1) ssum += __shfl_xor(ssum, off, 64);
  float inv = 1.0f / ssum;
  __shared__ float att[4][NS];
  __shared__ float pr[4][NCLS];
  att[wave][lane] = e1 * inv;
  if (lane < NS - 64) att[wave][lane + 64] = e2 * inv;
  __syncthreads();
  if (lane < NCLS) {
    const float* oh = onehot + ((size_t)b * NS) * NCLS + lane;
    float p = 0.f;
#pragma unroll 4
    for (int j = 0; j < NS; ++j) p += att[wave][j] * oh[(size_t)j * NCLS];
    out[(size_t)r * NCLS + lane] = p;
    pr[wave][lane] = p;
  }
  __syncthreads();
  if (lane == 0) {
    int best = 0;
    float bv = pr[wave][0];
    for (int c = 1; c < NCLS; ++c) {
      float v = pr[wave][c];
      if (v > bv) { bv = v; best = c; }
    }
    out[(size_t)MQ * NCLS + r] = (float)best;
  }
}

// ---------------------------------------------------------------------------
// Fallback fp32 GEMM path kernels (proven R1 path)
// ---------------------------------------------------------------------------
__global__ __launch_bounds__(256) void gemm_xw(const float* __restrict__ X,
                                               const float* __restrict__ W,
                                               const float* __restrict__ bias,
                                               float* __restrict__ Y) {
  __shared__ float As[16][64];
  __shared__ float Bs[16][64];
  const int t = threadIdx.x;
  const int row0 = blockIdx.x * 64;
  const int col0 = blockIdx.y * 64;
  const int am = t >> 2, ak = (t & 3) * 4;
  const int bk = t >> 4, bn = (t & 15) * 4;
  const int tm = (t >> 4) * 4, tn = (t & 15) * 4;
  float acc[4][4] = {};
  for (int k0 = 0; k0 < DIM; k0 += 16) {
    float4 av = *(const float4*)(X + (size_t)(row0 + am) * DIM + k0 + ak);
    As[ak + 0][am] = av.x;
    As[ak + 1][am] = av.y;
    As[ak + 2][am] = av.z;
    As[ak + 3][am] = av.w;
    *(float4*)&Bs[bk][bn] =
        *(const float4*)(W + (size_t)(k0 + bk) * DIM + col0 + bn);
    __syncthreads();
#pragma unroll
    for (int k = 0; k < 16; ++k) {
      float4 a4 = *(const float4*)&As[k][tm];
      float4 b4 = *(const float4*)&Bs[k][tn];
      float av_[4] = {a4.x, a4.y, a4.z, a4.w};
      float bv_[4] = {b4.x, b4.y, b4.z, b4.w};
#pragma unroll
      for (int i = 0; i < 4; ++i)
#pragma unroll
        for (int j = 0; j < 4; ++j) acc[i][j] += av_[i] * bv_[j];
    }
    __syncthreads();
  }
  float4 bbv = *(const float4*)(bias + col0 + tn);
  float bv_[4] = {bbv.x, bbv.y, bbv.z, bbv.w};
#pragma unroll
  for (int i = 0; i < 4; ++i) {
    float4 o;
    o.x = acc[i][0] + bv_[0];
    o.y = acc[i][1] + bv_[1];
    o.z = acc[i][2] + bv_[2];
    o.w = acc[i][3] + bv_[3];
    *(float4*)(Y + (size_t)(row0 + tm + i) * DIM + col0 + tn) = o;
  }
}

__global__ __launch_bounds__(256) void norm_kernel(const float* __restrict__ s,
                                                   float* __restrict__ inv_norm) {
  const int row = blockIdx.x;
  const float* p = s + (size_t)row * DIM;
  const int d0 = threadIdx.x * 8;
  float4 a = *(const float4*)(p + d0);
  float4 b = *(const float4*)(p + d0 + 4);
  float sum = a.x * a.x + a.y * a.y + a.z * a.z + a.w * a.w +
              b.x * b.x + b.y * b.y + b.z * b.z + b.w * b.w;
#pragma unroll
  for (int off = 32; off; off >>= 1) sum += __shfl_down(sum, off, 64);
  __shared__ float red[4];
  if ((threadIdx.x & 63) == 0) red[threadIdx.x >> 6] = sum;
  __syncthreads();
  if (threadIdx.x == 0) {
    float tot = red[0] + red[1] + red[2] + red[3];
    inv_norm[row] = rsqrtf(fmaxf(tot, 1e-10f));
  }
}

__global__ __launch_bounds__(256) void sim_kernel(const float* __restrict__ q,
                                                  const float* __restrict__ s,
                                                  const float* __restrict__ inv_norm,
                                                  float* __restrict__ sim) {
  __shared__ float As[16][64];
  __shared__ float Bs[16][64];
  const int t = threadIdx.x;
  const int b = blockIdx.z;
  const int row0 = blockIdx.y * 64;
  const int col0 = blockIdx.x * 64;
  const float* qb = q + (size_t)b * NQ * DIM;
  const float* sb = s + (size_t)b * NS * DIM;
  const int am = t >> 2, ak = (t & 3) * 4;
  const int tm = (t >> 4) * 4, tn = (t & 15) * 4;
  float acc[4][4] = {};
  for (int k0 = 0; k0 < DIM; k0 += 16) {
    float4 av = make_float4(0.f, 0.f, 0.f, 0.f);
    if (row0 + am < NQ)
      av = *(const float4*)(qb + (size_t)(row0 + am) * DIM + k0 + ak);
    As[ak + 0][am] = av.x;
    As[ak + 1][am] = av.y;
    As[ak + 2][am] = av.z;
    As[ak + 3][am] = av.w;
    float4 bv = make_float4(0.f, 0.f, 0.f, 0.f);
    if (col0 + am < NS)
      bv = *(const float4*)(sb + (size_t)(col0 + am) * DIM + k0 + ak);
    Bs[ak + 0][am] = bv.x;
    Bs[ak + 1][am] = bv.y;
    Bs[ak + 2][am] = bv.z;
    Bs[ak + 3][am] = bv.w;
    __syncthreads();
#pragma unroll
    for (int k = 0; k < 16; ++k) {
      float4 a4 = *(const float4*)&As[k][tm];
      float4 b4 = *(const float4*)&Bs[k][tn];
      float av_[4] = {a4.x, a4.y, a4.z, a4.w};
      float bv_[4] = {b4.x, b4.y, b4.z, b4.w};
#pragma unroll
      for (int i = 0; i < 4; ++i)
#pragma unroll
        for (int j = 0; j < 4; ++j) acc[i][j] += av_[i] * bv_[j];
    }
    __syncthreads();
  }
#pragma unroll
  for (int i = 0; i < 4; ++i) {
    int m = row0 + tm + i;
    if (m >= NQ) continue;
#pragma unroll
    for (int j = 0; j < 4; ++j) {
      int n = col0 + tn + j;
      if (n >= NS) continue;
      sim[((size_t)b * NQ + m) * NS + n] = acc[i][j] * inv_norm[b * NS + n];
    }
  }
}

// ---------------------------------------------------------------------------
extern "C" void kernel_launch(void* const* d_in, const int* in_sizes, int n_in,
                              void* d_out, int out_size, void* d_ws,
                              size_t ws_size, hipStream_t stream) {
  const float* support = (const float*)d_in[0];
  const float* query   = (const float*)d_in[1];
  const float* onehot  = (const float*)d_in[2];
  const float* W       = (const float*)d_in[3];
  const float* bias    = (const float*)d_in[4];

  char* wsb = (char*)d_ws;

  // --- Workspace layout (overlaid; lifetimes in comments) ---
  // S1   @ 0           26,214,400  [live: esplit2 .. Z-gemm]
  // S2   @ 26,214,400  26,214,400  [live: esplit2 .. Z-gemm]
  // Wr1  @ 52,428,800   8,388,608  [live: esplit2w .. G-gemm]
  // Wr2  @ 60,817,408   8,388,608  [live: esplit2w .. G-gemm]
  // G1   @ 69,206,016   8,388,608  [live: redG .. Z-gemm]
  // G2   @ 77,594,624   8,388,608  [live: redG .. Z-gemm]
  // Gp   @ 85,983,232  67,108,864  [live: G-gemm .. redG]
  // Zp   @ 85,983,232 104,857,600  [live: Z-gemm .. redZ]  (overlays Gp)
  // Z1   @ 0           26,214,400  [live: redZ .. sim2]    (overlays S1)
  // Z2   @ 26,214,400  26,214,400  [live: redZ .. sim2]    (overlays S2)
  // part @ 85,983,232  36,700,160  [live: sim2 .. softmax] (overlays Zp)
  // upart@ 122,683,392    327,680
  // wb   @ 190,840,832     8,192
  // bb   @ 190,849,024       256
  // inv  @ 190,849,280    25,600
  // vv   @ 190,874,880    25,600
  const size_t NEED = 190900480;

  if (ws_size >= NEED) {
    unsigned short* S1    = (unsigned short*)(wsb);
    unsigned short* S2    = (unsigned short*)(wsb + (size_t)26214400);
    unsigned short* Wr1   = (unsigned short*)(wsb + (size_t)52428800);
    unsigned short* Wr2   = (unsigned short*)(wsb + (size_t)60817408);
    unsigned short* G1    = (unsigned short*)(wsb + (size_t)69206016);
    unsigned short* G2    = (unsigned short*)(wsb + (size_t)77594624);
    float* Gp             = (float*)(wsb + (size_t)85983232);
    float* Zp             = (float*)(wsb + (size_t)85983232);
    unsigned short* Z1    = (unsigned short*)(wsb);
    unsigned short* Z2    = (unsigned short*)(wsb + (size_t)26214400);
    float* part           = (float*)(wsb + (size_t)85983232);
    float* upart          = (float*)(wsb + (size_t)122683392);
    float* wb             = (float*)(wsb + (size_t)190840832);
    float* bb             = (float*)(wsb + (size_t)190849024);
    float* inv_norm       = (float*)(wsb + (size_t)190849280);
    float* vv             = (float*)(wsb + (size_t)190874880);

    // W split + wb = W@b + bb (fused); support split
    esplit2w<<<DIM, 256, 0, stream>>>(W, bias, Wr1, Wr2, wb, bb);
    esplit2<<<MS * DIM / 1024, 256, 0, stream>>>(support, S1, S2,
                                                 MS * DIM / 4);
    // G = W @ W^T, all-bf16 128x256, k-split x4 -> 512 blocks (~2/CU)
    gemm_bb3k<4><<<dim3(DIM / 256, DIM / 128, 4), 256, 0, stream>>>(
        Wr1, Wr2, Wr1, Wr2, Gp);
    // sum 4 partials -> G1/G2 splits (G symmetric -> row split = [n][k] split)
    redG<<<DIM * DIM / 1024, 256, 0, stream>>>(Gp, G1, G2);
    // Z = Xs @ G, all-bf16 128x256, k-split x2 -> 800 blocks (~3/CU);
    // keeps 96 MFMA/barrier/wave (the R5/R6-isolated dominant factor).
    gemm_bb3k<2><<<dim3(DIM / 256, MS / 128, 2), 256, 0, stream>>>(
        S1, S2, G1, G2, Zp);
    // sum 2 partials -> Z1/Z2 splits + FUSED norm (inv_norm, vv)
    redZ<<<MS, 256, 0, stream>>>(Zp, support, wb, bb, Z1, Z2, inv_norm, vv);
    // sim partials (k-split x4, MFMA, LDS-free) + fused u = Xq.wb partials
    sim2_part<<<dim3(5, BATCH, KSPL), 256, 0, stream>>>(query, Z1, Z2, wb,
                                                        part, upart);
    // partial-sum + affine + softmax + onehot contract + argmax
    softmax_part<<<MQ / 4, 256, 0, stream>>>(part, upart, vv, bb, inv_norm,
                                             onehot, (float*)d_out);
  } else {
    // proven R1 fallback (fits in 217.5 MB)
    float* s = (float*)wsb;
    float* q = (float*)(wsb + (size_t)52428800);
    float* inv_norm = q + (size_t)MQ * DIM;
    float* sim      = inv_norm + MS;
    gemm_xw<<<dim3(MS / 64, DIM / 64), 256, 0, stream>>>(support, W, bias, s);
    gemm_xw<<<dim3(MQ / 64, DIM / 64), 256, 0, stream>>>(query, W, bias, q);
    norm_kernel<<<MS, 256, 0, stream>>>(s, inv_norm);
    sim_kernel<<<dim3(2, 5, BATCH), 256, 0, stream>>>(q, s, inv_norm, sim);
    softmax_fb<<<MQ / 4, 256, 0, stream>>>(sim, onehot, (float*)d_out);
  }
}